// Round 7
// baseline (448.540 us; speedup 1.0000x reference)
//
#include <hip/hip_runtime.h>
#include <hip/hip_bf16.h>
#include <hip/hip_fp8.h>
#include <stdint.h>

#define NTOK 196
#define NB   64
#define CCH  512
#define HID  2048
#define MTOT (NB * NTOK)   // 12544

typedef __attribute__((ext_vector_type(8))) short  short8v;
typedef __attribute__((ext_vector_type(4))) float  float4v;
typedef __attribute__((ext_vector_type(8))) int    int8v;
typedef __attribute__((ext_vector_type(4))) int    int4v;

union V8 { int8v v8; int4v v4[2]; };

// ---------------- helpers ----------------

__device__ __forceinline__ void mfma16x16(float4v& d, short8v a, short8v b) {
  asm("v_mfma_f32_16x16x32_bf16 %0, %1, %2, %0" : "+v"(d) : "v"(a), "v"(b));
}

__device__ __forceinline__ void gload_lds16(const void* gsrc, void* ldst) {
  __builtin_amdgcn_global_load_lds(
      (const __attribute__((address_space(1))) unsigned int*)gsrc,
      (__attribute__((address_space(3))) unsigned int*)ldst, 16, 0, 0);
}

__device__ __forceinline__ int swz4(int r) { return (r ^ (r >> 2)) & 3; }

__device__ __forceinline__ uint8_t to_fp8(float v) {
  return __hip_fp8_e4m3(v).__x;
}

// ---------------- prep: BN constants ----------------

__global__ void prep_consts(const float* __restrict__ bn_g, const float* __restrict__ bn_b,
                            const float* __restrict__ bn_m, const float* __restrict__ bn_v,
                            const float* __restrict__ fbn_g, const float* __restrict__ fbn_b,
                            const float* __restrict__ fbn_m, const float* __restrict__ fbn_v,
                            float* __restrict__ cst) {
  int c = blockIdx.x * blockDim.x + threadIdx.x;
  if (c < CCH) {
    float i1 = bn_g[c] * rsqrtf(bn_v[c] + 1e-5f);
    cst[c] = i1;
    cst[512 + c] = bn_b[c] - bn_m[c] * i1;
    float i2 = fbn_g[c] * rsqrtf(fbn_v[c] + 1e-5f);
    cst[1024 + c] = i2;
    cst[1536 + c] = fbn_b[c] - fbn_m[c] * i2;
  }
}

// ---------------- weights fp32 -> fp8 e4m3, x16, BN scale folded ----------------

__global__ void cvt_weights(const float* __restrict__ qkv_w, const float* __restrict__ proj_w,
                            const float* __restrict__ fc1_w, const float* __restrict__ fc2_w,
                            const float* __restrict__ cst,
                            uint8_t* __restrict__ qkvb, uint8_t* __restrict__ projb,
                            uint8_t* __restrict__ fc1b, uint8_t* __restrict__ fc2b) {
  int i4 = blockIdx.x * blockDim.x + threadIdx.x;    // unit = 4 floats
  const int nq = 1536 * 512 / 4;
  const int np = 512 * 512 / 4;
  const int n1 = 2048 * 512 / 4;
  const float* src;
  uint8_t* dst;
  const float* scl = nullptr;
  int k;
  if (i4 < nq)                { src = qkv_w;  dst = qkvb;  k = i4; scl = cst; }
  else if (i4 < nq + np)      { src = proj_w; dst = projb; k = i4 - nq; }
  else if (i4 < nq + np + n1) { src = fc1_w;  dst = fc1b;  k = i4 - nq - np; scl = cst + 1024; }
  else                        { src = fc2_w;  dst = fc2b;  k = i4 - nq - np - n1; }
  float4v v = *(const float4v*)(src + 4 * (size_t)k);
  int c0 = (4 * k) & 511;
  #pragma unroll
  for (int l = 0; l < 4; ++l) {
    float f = v[l] * 16.0f;
    if (scl) f *= scl[c0 + l];
    dst[4 * (size_t)k + l] = to_fp8(f);
  }
}

// ---------------- folded biases: qb[o] = sum_c qkv_w[o,c]*t1[c]; fb1 likewise ----------------

__global__ __launch_bounds__(128) void prep_bias(
    const float* __restrict__ qkv_w, const float* __restrict__ fc1_w,
    const float* __restrict__ fc1_b, const float* __restrict__ cst,
    float* __restrict__ qb, float* __restrict__ fb1) {
  __shared__ float partial[2];
  const int o = blockIdx.x;            // 0..3583
  const int t = threadIdx.x;
  const float* w;
  const float* tv;
  float base = 0.f;
  if (o < 1536) { w = qkv_w + (size_t)o * 512; tv = cst + 512; }
  else          { w = fc1_w + (size_t)(o - 1536) * 512; tv = cst + 1536; base = fc1_b[o - 1536]; }
  int c = t * 4;
  float s = 0.f;
  #pragma unroll
  for (int e = 0; e < 4; ++e) s += w[c + e] * tv[c + e];
  #pragma unroll
  for (int off = 32; off >= 1; off >>= 1) s += __shfl_down(s, off);
  if ((t & 63) == 0) partial[t >> 6] = s;
  __syncthreads();
  if (t == 0) {
    float tot = base + partial[0] + partial[1];
    if (o < 1536) qb[o] = tot; else fb1[o - 1536] = tot;
  }
}

// ---------------- transpose NCHW fp32 -> token-major bf16 + fp8 ----------------

__global__ __launch_bounds__(256) void transpose_x(
    const float* __restrict__ x, __hip_bfloat16* __restrict__ xtb,
    uint8_t* __restrict__ xt8) {
  __shared__ float tile[32][33];
  const int n0 = blockIdx.x * 32;
  const int c0 = blockIdx.y * 32;
  const int b  = blockIdx.z;
  const int j = threadIdx.x & 31, i = threadIdx.x >> 5;
  #pragma unroll
  for (int p = 0; p < 4; ++p) {
    int cc = c0 + i + p * 8;
    int n = n0 + j;
    if (n < NTOK) tile[i + p * 8][j] = x[((size_t)b * CCH + cc) * NTOK + n];
  }
  __syncthreads();
  #pragma unroll
  for (int p = 0; p < 4; ++p) {
    int n = n0 + i + p * 8;
    int cc = c0 + j;
    if (n < NTOK) {
      float raw = tile[j][i + p * 8];
      size_t o = ((size_t)b * NTOK + n) * CCH + cc;
      xtb[o] = __float2bfloat16(raw);
      xt8[o] = to_fp8(raw);
    }
  }
}

// ---------------- MX-fp8 GEMM: C[M,N] = A[M,K]*B[N,K]^T (B pre-scaled x16) ----------------
// BM=BN=128, 256 thr = 4 waves (2x2), per-wave 64x64. K in 512-chunks:
// stage whole B-chunk (64KB, 16B-chunk XOR swizzle) -> ONE barrier -> 4 pure-compute
// k-steps of mfma_scale_f32_16x16x128_f8f6f4 with A streamed global->reg.
// Epilogue applies acc/16.  EPI: 0=qkv bf16+bias  1=proj x1t=xtb+ls1*(v+b)
//                                2=fc1 gelu->fp8  3=fc2 -> NCHW fp32 (LDS transpose)

template<int EPI>
__global__ __launch_bounds__(256, 2) void gemm8(
    const uint8_t* __restrict__ A, const uint8_t* __restrict__ Bw,
    int N, int K, int NY,
    __hip_bfloat16* __restrict__ outb, uint8_t* __restrict__ out8,
    float* __restrict__ outf,
    const float* __restrict__ bias, const float* __restrict__ ls,
    const __hip_bfloat16* __restrict__ resid) {
  __shared__ char ldsB[65536];   // 128 rows x 512B (one 512-K chunk of B, fp8)
  const int tid  = threadIdx.x;
  const int lane = tid & 63;
  const int wave = tid >> 6;

  // bijective XCD swizzle (m204); by-fast => consecutive blocks share A-panel
  const int nwg = (int)gridDim.x;
  const int q8 = nwg >> 3, r8 = nwg & 7;
  const int orig = blockIdx.x;
  const int xcd = orig & 7;
  const int wgid = (xcd < r8 ? xcd * (q8 + 1) : r8 * (q8 + 1) + (xcd - r8) * q8) + (orig >> 3);
  const int bx = wgid / NY;
  const int by = wgid - bx * NY;

  const int m0 = bx * 128;
  const int n0 = by * 128;
  const int wm = (wave >> 1) * 64;
  const int wn = (wave & 1) * 64;
  const int NCH = K >> 9;              // 512-k chunks

  float4v acc[4][4] = {};

  const uint8_t* Ap = A + (size_t)(m0 + wm + (lane & 15)) * K + ((lane >> 4) << 5);

  auto stageB = [&](int ch) {          // 64KB, 16B-granule XOR swizzle in low-3 chunk bits
    #pragma unroll
    for (int s = 0; s < 16; ++s) {
      int L = s * 4096 + tid * 16;
      int r  = L >> 9;                 // 0..127
      int pc = (L >> 4) & 31;
      int lc = (pc & 24) | ((pc ^ r) & 7);
      gload_lds16(Bw + (size_t)(n0 + r) * K + (ch << 9) + lc * 16, ldsB + L);
    }
  };

  for (int ch = 0; ch < NCH; ++ch) {
    stageB(ch);
    __syncthreads();
    #pragma unroll
    for (int ks = 0; ks < 4; ++ks) {
      const int kofs = (ch << 9) + (ks << 7);
      int8v af[4];
      #pragma unroll
      for (int i = 0; i < 4; ++i) {
        V8 u;
        u.v4[0] = *(const int4v*)(Ap + (size_t)i * 16 * K + kofs);
        u.v4[1] = *(const int4v*)(Ap + (size_t)i * 16 * K + kofs + 16);
        af[i] = u.v8;
      }
      int8v bf[4];
      #pragma unroll
      for (int j = 0; j < 4; ++j) {
        int r = wn + j * 16 + (lane & 15);
        int cl = (ks << 3) + ((lane >> 4) << 1);
        int pc0 = (cl & 24) | ((cl ^ r) & 7);
        int pc1 = (cl & 24) | (((cl + 1) ^ r) & 7);
        V8 u;
        u.v4[0] = *(const int4v*)(ldsB + r * 512 + pc0 * 16);
        u.v4[1] = *(const int4v*)(ldsB + r * 512 + pc1 * 16);
        bf[j] = u.v8;
      }
      #pragma unroll
      for (int i = 0; i < 4; ++i)
        #pragma unroll
        for (int j = 0; j < 4; ++j)
          acc[i][j] = __builtin_amdgcn_mfma_scale_f32_16x16x128_f8f6f4(
              af[i], bf[j], acc[i][j], 0, 0, 0, 0x7F7F7F7F, 0, 0x7F7F7F7F);
    }
    if (ch + 1 < NCH) __syncthreads();
  }
  const float RS = 0.0625f;            // undo weight x16

  if (EPI == 0 || EPI == 2) {
    #pragma unroll
    for (int i = 0; i < 4; ++i)
      #pragma unroll
      for (int j = 0; j < 4; ++j)
        #pragma unroll
        for (int r = 0; r < 4; ++r) {
          int m = m0 + wm + i * 16 + ((lane >> 4) << 2) + r;
          int n = n0 + wn + j * 16 + (lane & 15);
          float v = acc[i][j][r] * RS + bias[n];
          if (EPI == 0) {
            outb[(size_t)m * N + n] = __float2bfloat16(v);
          } else {
            float g = v / (1.0f + __expf(-1.702f * v));   // fast GELU (x1e-5 after ls2)
            out8[(size_t)m * N + n] = to_fp8(g);
          }
        }
  } else if (EPI == 1) {
    #pragma unroll
    for (int i = 0; i < 4; ++i)
      #pragma unroll
      for (int j = 0; j < 4; ++j)
        #pragma unroll
        for (int r = 0; r < 4; ++r) {
          int m = m0 + wm + i * 16 + ((lane >> 4) << 2) + r;
          int n = n0 + wn + j * 16 + (lane & 15);
          float v = acc[i][j][r] * RS + bias[n];
          v = __bfloat162float(resid[(size_t)m * CCH + n]) + ls[n] * v;
          outb[(size_t)m * CCH + n] = __float2bfloat16(v);
        }
  } else {   // EPI == 3 : epilogue + in-LDS transpose -> NCHW fp32, 4 passes of 32 n
    float* LT = (float*)ldsB;          // [32][132] fp32 = 16.9KB
    #pragma unroll 1
    for (int s = 0; s < 4; ++s) {
      __syncthreads();
      if (wn == (s >> 1) * 64) {
        const int j0 = (s & 1) * 2;
        #pragma unroll
        for (int i = 0; i < 4; ++i)
          #pragma unroll
          for (int jj = 0; jj < 2; ++jj)
            #pragma unroll
            for (int r = 0; r < 4; ++r) {
              int ml = wm + i * 16 + ((lane >> 4) << 2) + r;   // 0..127
              int nl = jj * 16 + (lane & 15);                   // 0..31
              int ng = n0 + s * 32 + nl;
              float v = acc[i][j0 + jj][r] * RS + bias[ng];
              v = __bfloat162float(resid[(size_t)(m0 + ml) * CCH + ng]) + ls[ng] * v;
              LT[nl * 132 + ml] = v;
            }
      }
      __syncthreads();
      #pragma unroll
      for (int u = 0; u < 4; ++u) {
        int q = tid + 256 * u;         // 0..1023 = 32 nl x 32 mq
        int nl = q >> 5;
        int mq = q & 31;
        int ng = n0 + s * 32 + nl;
        int ml = mq * 4;
        float4v v4 = *(const float4v*)(LT + nl * 132 + ml);
        int m = m0 + ml;
        int bb = m / NTOK, tt = m - bb * NTOK;   // tt multiple of 4; 196%4==0 -> no row cross
        *(float4v*)(outf + (size_t)bb * (CCH * NTOK) + (size_t)ng * NTOK + tt) = v4;
      }
    }
  }
}

// ---------------- attention: one block per (batch, head), bf16; fp8 out ----------------

__global__ __launch_bounds__(256, 2) void attn_kernel(
    const __hip_bfloat16* __restrict__ qkv, uint8_t* __restrict__ o_t8) {
  __shared__ char sQ[208 * 64];    // [208][32] bf16, chunk-swizzled rows
  __shared__ char sK[224 * 64];    // [224][32] bf16
  __shared__ char sV[32 * 448];    // V^T [32][224] bf16, chunk-swizzled
  __shared__ char sP[4][16 * 472]; // per-wave P [16][236] bf16
  const int tid  = threadIdx.x;
  const int lane = tid & 63;
  const int wave = tid >> 6;
  const int b = blockIdx.x >> 4;
  const int h = blockIdx.x & 15;
  const size_t qbase = (size_t)b * NTOK * 1536 + h * 32;

  {
    uint32_t* z = (uint32_t*)sQ;
    for (int i = tid; i < (208 * 64) / 4; i += 256) z[i] = 0u;
    z = (uint32_t*)sK;
    for (int i = tid; i < (224 * 64) / 4; i += 256) z[i] = 0u;
    z = (uint32_t*)sV;
    for (int i = tid; i < (32 * 448) / 4; i += 256) z[i] = 0u;
  }
  __syncthreads();

  for (int p = tid; p < NTOK * 4; p += 256) {
    int row = p >> 2, c = p & 3;
    const __hip_bfloat16* src = qkv + qbase + (size_t)row * 1536 + c * 8;
    short8v q = *(const short8v*)(src);
    short8v k = *(const short8v*)(src + 512);
    short8v v = *(const short8v*)(src + 1024);
    int pc = c ^ swz4(row);
    *(short8v*)(sQ + row * 64 + pc * 16) = q;
    *(short8v*)(sK + row * 64 + pc * 16) = k;
    #pragma unroll
    for (int j = 0; j < 8; ++j) {
      int d = c * 8 + j;
      int ch = (row >> 3) ^ swz4(d);
      *(uint16_t*)(sV + d * 448 + ch * 16 + (row & 7) * 2) = (uint16_t)v[j];
    }
  }
  __syncthreads();

  const float scale = 0.17677669529663687f;   // 1/sqrt(32)
  char* Pw = sP[wave];

  for (int mt = wave; mt < 13; mt += 4) {
    int qrow = mt * 16 + (lane & 15);
    int pcq = (lane >> 4) ^ swz4(qrow);
    short8v aq = *(const short8v*)(sQ + qrow * 64 + pcq * 16);

    float4v s[14];
    #pragma unroll
    for (int nt = 0; nt < 14; ++nt) {
      int krow = nt * 16 + (lane & 15);
      int pck = (lane >> 4) ^ swz4(krow);
      short8v bk = *(const short8v*)(sK + krow * 64 + pck * 16);
      s[nt] = float4v{0.f, 0.f, 0.f, 0.f};
      mfma16x16(s[nt], aq, bk);
    }
    asm volatile("s_nop 7\n\ts_nop 7");

    float mx[4] = {-INFINITY, -INFINITY, -INFINITY, -INFINITY};
    #pragma unroll
    for (int nt = 0; nt < 14; ++nt) {
      bool valid = (nt * 16 + (lane & 15)) < NTOK;
      #pragma unroll
      for (int r = 0; r < 4; ++r) {
        float v = valid ? s[nt][r] * scale : -INFINITY;
        s[nt][r] = v;
        mx[r] = fmaxf(mx[r], v);
      }
    }
    #pragma unroll
    for (int off = 1; off < 16; off <<= 1) {
      #pragma unroll
      for (int r = 0; r < 4; ++r) mx[r] = fmaxf(mx[r], __shfl_xor(mx[r], off));
    }
    float sum[4] = {0.f, 0.f, 0.f, 0.f};
    #pragma unroll
    for (int nt = 0; nt < 14; ++nt) {
      #pragma unroll
      for (int r = 0; r < 4; ++r) {
        float e = __expf(s[nt][r] - mx[r]);
        s[nt][r] = e;
        sum[r] += e;
      }
    }
    #pragma unroll
    for (int off = 1; off < 16; off <<= 1) {
      #pragma unroll
      for (int r = 0; r < 4; ++r) sum[r] += __shfl_xor(sum[r], off);
    }
    float rs[4];
    #pragma unroll
    for (int r = 0; r < 4; ++r) rs[r] = 1.0f / sum[r];

    #pragma unroll
    for (int nt = 0; nt < 14; ++nt) {
      int col = nt * 16 + (lane & 15);
      #pragma unroll
      for (int r = 0; r < 4; ++r) {
        int prow = ((lane >> 4) << 2) + r;
        *(__hip_bfloat16*)(Pw + prow * 472 + col * 2) = __float2bfloat16(s[nt][r] * rs[r]);
      }
    }

    float4v o0 = float4v{0.f, 0.f, 0.f, 0.f};
    float4v o1 = float4v{0.f, 0.f, 0.f, 0.f};
    #pragma unroll
    for (int ks = 0; ks < 7; ++ks) {
      short8v pa = *(const short8v*)(Pw + (lane & 15) * 472 + ks * 64 + ((lane >> 4) << 4));
      int kc = ks * 4 + (lane >> 4);
      int d0 = (lane & 15);
      int d1 = 16 + (lane & 15);
      short8v v0 = *(const short8v*)(sV + d0 * 448 + ((kc ^ swz4(d0)) << 4));
      short8v v1 = *(const short8v*)(sV + d1 * 448 + ((kc ^ swz4(d1)) << 4));
      mfma16x16(o0, pa, v0);
      mfma16x16(o1, pa, v1);
    }
    asm volatile("s_nop 7\n\ts_nop 7");

    #pragma unroll
    for (int r = 0; r < 4; ++r) {
      int trow = mt * 16 + ((lane >> 4) << 2) + r;
      if (trow < NTOK) {
        size_t ob = ((size_t)b * NTOK + trow) * CCH + h * 32 + (lane & 15);
        o_t8[ob] = to_fp8(o0[r]);
        o_t8[ob + 16] = to_fp8(o1[r]);
      }
    }
  }
}

// ---------------- depthwise 7x7 conv, token-major (+BN in, raw fp8 out) ----------------

__global__ __launch_bounds__(448) void dwconv_tm(
    const __hip_bfloat16* __restrict__ x1t, const float* __restrict__ dw_w,
    const float* __restrict__ cst, uint8_t* __restrict__ yt8) {
  __shared__ float img[196][32];
  __shared__ float wgt[49][32];
  const int tid = threadIdx.x;
  const int b  = blockIdx.x >> 4;
  const int cb = (blockIdx.x & 15) * 32;
  const int c  = tid & 31;
  const int gc = cb + c;
  const float s = cst[gc], t0 = cst[512 + gc];
  #pragma unroll
  for (int k = 0; k < 14; ++k) {
    int p = (tid >> 5) + k * 14;
    img[p][c] = __bfloat162float(x1t[((size_t)b * NTOK + p) * CCH + gc]) * s + t0;
  }
  for (int i = tid; i < 49 * 32; i += 448) {
    int tap = i >> 5, cc = i & 31;
    wgt[tap][cc] = dw_w[(cb + cc) * 49 + tap];
  }
  __syncthreads();

  const int px = tid >> 5;        // 0..13
  float out[14];
  #pragma unroll
  for (int i = 0; i < 14; ++i) out[i] = 0.f;
  #pragma unroll 1
  for (int row = 0; row < 14; ++row) {
    float v[7];
    #pragma unroll
    for (int dx = 0; dx < 7; ++dx) {
      int ix = px + dx - 3;
      v[dx] = ((unsigned)ix < 14u) ? img[row * 14 + ix][c] : 0.f;
    }
    #pragma unroll
    for (int kk = 0; kk < 7; ++kk) {
      int py = row + 3 - kk;
      if (py >= 0 && py < 14) {
        float hsum = 0.f;
        #pragma unroll
        for (int dx = 0; dx < 7; ++dx) hsum = fmaf(v[dx], wgt[kk * 7 + dx][c], hsum);
        out[py] += hsum;
      }
    }
  }
  #pragma unroll
  for (int py = 0; py < 14; ++py)
    yt8[((size_t)b * NTOK + py * 14 + px) * CCH + gc] = to_fp8(out[py]);
}

// ---------------- launch ----------------

extern "C" void kernel_launch(void* const* d_in, const int* in_sizes, int n_in,
                              void* d_out, int out_size, void* d_ws, size_t ws_size,
                              hipStream_t stream) {
  const float* x      = (const float*)d_in[0];
  const float* bn_g   = (const float*)d_in[1];
  const float* bn_b   = (const float*)d_in[2];
  const float* bn_m   = (const float*)d_in[3];
  const float* bn_v   = (const float*)d_in[4];
  const float* qkv_w  = (const float*)d_in[5];
  const float* proj_w = (const float*)d_in[6];
  const float* proj_b = (const float*)d_in[7];
  const float* dw_w   = (const float*)d_in[8];
  const float* fbn_g  = (const float*)d_in[9];
  const float* fbn_b  = (const float*)d_in[10];
  const float* fbn_m  = (const float*)d_in[11];
  const float* fbn_v  = (const float*)d_in[12];
  const float* fc1_w  = (const float*)d_in[13];
  const float* fc1_b  = (const float*)d_in[14];
  const float* fc2_w  = (const float*)d_in[15];
  const float* fc2_b  = (const float*)d_in[16];
  const float* ls1    = (const float*)d_in[17];
  const float* ls2    = (const float*)d_in[18];

  char* ws = (char*)d_ws;
  float* cst             = (float*)ws;                        // 8 KB
  float* qb              = (float*)(ws + 8192);               // 6 KB
  float* fb1             = (float*)(ws + 14336);              // 8 KB
  uint8_t* qkvb8         = (uint8_t*)(ws + 32768);            // 768 KB
  uint8_t* projb8        = (uint8_t*)(ws + 819200);           // 256 KB
  uint8_t* fc1b8         = (uint8_t*)(ws + 1081344);          // 1 MB
  uint8_t* fc2b8         = (uint8_t*)(ws + 2129920);          // 1 MB
  uint8_t* xt8           = (uint8_t*)(ws + 3178496);          // 6.4 MB
  __hip_bfloat16* xtb    = (__hip_bfloat16*)(ws + 9601024);   // 12.85 MB
  __hip_bfloat16* qkvt   = (__hip_bfloat16*)(ws + 22446080);  // 38.5 MB
  uint8_t* ot8           = (uint8_t*)(ws + 60981248);         // 6.4 MB
  __hip_bfloat16* x1t    = (__hip_bfloat16*)(ws + 67403776);  // 12.85 MB
  uint8_t* yt8           = (uint8_t*)(ws + 80248832);         // 6.4 MB (end 86.7 MB)
  uint8_t* h8            = (uint8_t*)(ws + 3178496);          // 25.7 MB overlay (xt8/xtb/qkvt dead)

  prep_consts<<<dim3(2), dim3(256), 0, stream>>>(bn_g, bn_b, bn_m, bn_v,
                                                 fbn_g, fbn_b, fbn_m, fbn_v, cst);
  cvt_weights<<<dim3(3072), dim3(256), 0, stream>>>(qkv_w, proj_w, fc1_w, fc2_w, cst,
                                                    qkvb8, projb8, fc1b8, fc2b8);
  prep_bias<<<dim3(3584), dim3(128), 0, stream>>>(qkv_w, fc1_w, fc1_b, cst, qb, fb1);
  transpose_x<<<dim3(7, 16, 64), dim3(256), 0, stream>>>(x, xtb, xt8);
  // QKV: M=12544, N=1536, K=512 ; 128x128 -> 98*12 = 1176 blocks
  gemm8<0><<<dim3(1176), dim3(256), 0, stream>>>(xt8, qkvb8, 1536, 512, 12,
                                                 qkvt, nullptr, nullptr, qb, nullptr, nullptr);
  attn_kernel<<<dim3(1024), dim3(256), 0, stream>>>(qkvt, ot8);
  // proj: N=512, K=512 ; 98*4 = 392 blocks
  gemm8<1><<<dim3(392), dim3(256), 0, stream>>>(ot8, projb8, 512, 512, 4,
                                                x1t, nullptr, nullptr, proj_b, ls1, xtb);
  dwconv_tm<<<dim3(1024), dim3(448), 0, stream>>>(x1t, dw_w, cst, yt8);
  // fc1: N=2048, K=512 ; 98*16 = 1568 blocks
  gemm8<2><<<dim3(1568), dim3(256), 0, stream>>>(yt8, fc1b8, 2048, 512, 16,
                                                 nullptr, h8, nullptr, fb1, nullptr, nullptr);
  // fc2: N=512, K=2048 ; 392 blocks ; NCHW fp32 out
  gemm8<3><<<dim3(392), dim3(256), 0, stream>>>(h8, fc2b8, 512, 2048, 4,
                                                nullptr, nullptr, (float*)d_out, fc2_b, ls2, x1t);
}

// Round 8
// 301.399 us; speedup vs baseline: 1.4882x; 1.4882x over previous
//
#include <hip/hip_runtime.h>
#include <hip/hip_bf16.h>
#include <hip/hip_fp8.h>
#include <stdint.h>

#define NTOK 196
#define NB   64
#define CCH  512
#define HID  2048
#define MTOT (NB * NTOK)   // 12544

typedef __attribute__((ext_vector_type(8))) short  short8v;
typedef __attribute__((ext_vector_type(4))) float  float4v;
typedef __attribute__((ext_vector_type(8))) int    int8v;
typedef __attribute__((ext_vector_type(4))) int    int4v;

// ---------------- helpers ----------------

__device__ __forceinline__ void mfma16x16(float4v& d, short8v a, short8v b) {
  asm("v_mfma_f32_16x16x32_bf16 %0, %1, %2, %0" : "+v"(d) : "v"(a), "v"(b));
}

__device__ __forceinline__ void gload_lds16(const void* gsrc, void* ldst) {
  __builtin_amdgcn_global_load_lds(
      (const __attribute__((address_space(1))) unsigned int*)gsrc,
      (__attribute__((address_space(3))) unsigned int*)ldst, 16, 0, 0);
}

__device__ __forceinline__ int swz4(int r) { return (r ^ (r >> 2)) & 3; }

__device__ __forceinline__ uint8_t to_fp8(float v) {
  return __hip_fp8_e4m3(v).__x;
}

// read one 32B fp8 operand (two swizzled 16B chunks) from LDS, register-only assembly
__device__ __forceinline__ int8v lds_op32(const char* rowbase, int r, int c2) {
  int p0 = (c2)     ^ (r & 7);
  int p1 = (c2 + 1) ^ (r & 7);
  int4v lo = *(const int4v*)(rowbase + p0 * 16);
  int4v hi = *(const int4v*)(rowbase + p1 * 16);
  return __builtin_shufflevector(lo, hi, 0, 1, 2, 3, 4, 5, 6, 7);
}

// ---------------- prep: BN constants ----------------

__global__ void prep_consts(const float* __restrict__ bn_g, const float* __restrict__ bn_b,
                            const float* __restrict__ bn_m, const float* __restrict__ bn_v,
                            const float* __restrict__ fbn_g, const float* __restrict__ fbn_b,
                            const float* __restrict__ fbn_m, const float* __restrict__ fbn_v,
                            float* __restrict__ cst) {
  int c = blockIdx.x * blockDim.x + threadIdx.x;
  if (c < CCH) {
    float i1 = bn_g[c] * rsqrtf(bn_v[c] + 1e-5f);
    cst[c] = i1;
    cst[512 + c] = bn_b[c] - bn_m[c] * i1;
    float i2 = fbn_g[c] * rsqrtf(fbn_v[c] + 1e-5f);
    cst[1024 + c] = i2;
    cst[1536 + c] = fbn_b[c] - fbn_m[c] * i2;
  }
}

// ---------------- weights fp32 -> fp8 e4m3, x16, BN scale folded ----------------

__global__ void cvt_weights(const float* __restrict__ qkv_w, const float* __restrict__ proj_w,
                            const float* __restrict__ fc1_w, const float* __restrict__ fc2_w,
                            const float* __restrict__ cst,
                            uint8_t* __restrict__ qkvb, uint8_t* __restrict__ projb,
                            uint8_t* __restrict__ fc1b, uint8_t* __restrict__ fc2b) {
  int i4 = blockIdx.x * blockDim.x + threadIdx.x;    // unit = 4 floats
  const int nq = 1536 * 512 / 4;
  const int np = 512 * 512 / 4;
  const int n1 = 2048 * 512 / 4;
  const float* src;
  uint8_t* dst;
  const float* scl = nullptr;
  int k;
  if (i4 < nq)                { src = qkv_w;  dst = qkvb;  k = i4; scl = cst; }
  else if (i4 < nq + np)      { src = proj_w; dst = projb; k = i4 - nq; }
  else if (i4 < nq + np + n1) { src = fc1_w;  dst = fc1b;  k = i4 - nq - np; scl = cst + 1024; }
  else                        { src = fc2_w;  dst = fc2b;  k = i4 - nq - np - n1; }
  float4v v = *(const float4v*)(src + 4 * (size_t)k);
  int c0 = (4 * k) & 511;
  #pragma unroll
  for (int l = 0; l < 4; ++l) {
    float f = v[l] * 16.0f;
    if (scl) f *= scl[c0 + l];
    dst[4 * (size_t)k + l] = to_fp8(f);
  }
}

// ---------------- folded biases: qb[o] = sum_c qkv_w[o,c]*t1[c]; fb1 likewise ----------------

__global__ __launch_bounds__(128) void prep_bias(
    const float* __restrict__ qkv_w, const float* __restrict__ fc1_w,
    const float* __restrict__ fc1_b, const float* __restrict__ cst,
    float* __restrict__ qb, float* __restrict__ fb1) {
  __shared__ float partial[2];
  const int o = blockIdx.x;            // 0..3583
  const int t = threadIdx.x;
  const float* w;
  const float* tv;
  float base = 0.f;
  if (o < 1536) { w = qkv_w + (size_t)o * 512; tv = cst + 512; }
  else          { w = fc1_w + (size_t)(o - 1536) * 512; tv = cst + 1536; base = fc1_b[o - 1536]; }
  int c = t * 4;
  float s = 0.f;
  #pragma unroll
  for (int e = 0; e < 4; ++e) s += w[c + e] * tv[c + e];
  #pragma unroll
  for (int off = 32; off >= 1; off >>= 1) s += __shfl_down(s, off);
  if ((t & 63) == 0) partial[t >> 6] = s;
  __syncthreads();
  if (t == 0) {
    float tot = base + partial[0] + partial[1];
    if (o < 1536) qb[o] = tot; else fb1[o - 1536] = tot;
  }
}

// ---------------- transpose NCHW fp32 -> token-major bf16 + fp8 ----------------

__global__ __launch_bounds__(256) void transpose_x(
    const float* __restrict__ x, __hip_bfloat16* __restrict__ xtb,
    uint8_t* __restrict__ xt8) {
  __shared__ float tile[32][33];
  const int n0 = blockIdx.x * 32;
  const int c0 = blockIdx.y * 32;
  const int b  = blockIdx.z;
  const int j = threadIdx.x & 31, i = threadIdx.x >> 5;
  #pragma unroll
  for (int p = 0; p < 4; ++p) {
    int cc = c0 + i + p * 8;
    int n = n0 + j;
    if (n < NTOK) tile[i + p * 8][j] = x[((size_t)b * CCH + cc) * NTOK + n];
  }
  __syncthreads();
  #pragma unroll
  for (int p = 0; p < 4; ++p) {
    int n = n0 + i + p * 8;
    int cc = c0 + j;
    if (n < NTOK) {
      float raw = tile[j][i + p * 8];
      size_t o = ((size_t)b * NTOK + n) * CCH + cc;
      xtb[o] = __float2bfloat16(raw);
      xt8[o] = to_fp8(raw);
    }
  }
}

// ---------------- MX-fp8 GEMM (m148-style): C[M,N]=A[M,K]*B[N,K]^T, B pre-scaled x16 ----------
// BM=BN=128, 4 waves (2x2), per-wave 64x64. BK=128 (one mfma_scale K-depth).
// A+B staged in LDS (16KB+16KB per buf, dbuf=64KB), 2-phase __syncthreads loop,
// 16B-chunk XOR swizzle both sides, register-only operand assembly (shufflevector).
// Epilogue applies acc/16.  EPI: 0=qkv bf16+bias  1=proj x1t=xtb+ls1*(v+b)
//                                2=fc1 gelu->fp8  3=fc2 -> NCHW fp32 (LDS transpose)

template<int EPI>
__global__ __launch_bounds__(256, 2) void gemm8(
    const uint8_t* __restrict__ A, const uint8_t* __restrict__ Bw,
    int N, int K, int NY,
    __hip_bfloat16* __restrict__ outb, uint8_t* __restrict__ out8,
    float* __restrict__ outf,
    const float* __restrict__ bias, const float* __restrict__ ls,
    const __hip_bfloat16* __restrict__ resid) {
  __shared__ char lds[65536];          // 2 bufs x (A 16KB + B 16KB)
  const int tid  = threadIdx.x;
  const int lane = tid & 63;
  const int wave = tid >> 6;

  // bijective XCD swizzle (m204); by-fast => consecutive blocks share A-panel
  const int nwg = (int)gridDim.x;
  const int q8 = nwg >> 3, r8 = nwg & 7;
  const int orig = blockIdx.x;
  const int xcd = orig & 7;
  const int wgid = (xcd < r8 ? xcd * (q8 + 1) : r8 * (q8 + 1) + (xcd - r8) * q8) + (orig >> 3);
  const int bx = wgid / NY;
  const int by = wgid - bx * NY;

  const int m0 = bx * 128;
  const int n0 = by * 128;
  const int wm = (wave >> 1) * 64;
  const int wn = (wave & 1) * 64;
  const int KT = K >> 7;               // K-steps of 128

  float4v acc[4][4] = {};

  // stage one 128-deep K-slice of A and B (16KB each) into buf; src chunk pre-swizzled
  auto stage = [&](int buf, int kt) {
    char* base = lds + buf * 32768;
    const int kb = kt << 7;
    #pragma unroll
    for (int s = 0; s < 4; ++s) {      // A: 128 rows x 128B
      int L = s * 4096 + tid * 16;
      int r = L >> 7, pc = (L >> 4) & 7, lc = pc ^ (r & 7);
      gload_lds16(A + (size_t)(m0 + r) * K + kb + lc * 16, base + L);
    }
    #pragma unroll
    for (int s = 0; s < 4; ++s) {      // B: 128 rows x 128B
      int L = s * 4096 + tid * 16;
      int r = L >> 7, pc = (L >> 4) & 7, lc = pc ^ (r & 7);
      gload_lds16(Bw + (size_t)(n0 + r) * K + kb + lc * 16, base + 16384 + L);
    }
  };

  stage(0, 0);
  __syncthreads();
  #pragma unroll 1
  for (int kt = 0; kt < KT; ++kt) {
    if (kt + 1 < KT) stage((kt + 1) & 1, kt + 1);
    const char* bA = lds + (kt & 1) * 32768;
    const char* bB = bA + 16384;
    const int c2 = (lane >> 4) << 1;   // 16B-chunk pair index (0,2,4,6)
    #pragma unroll
    for (int i = 0; i < 4; ++i) {
      int ra = wm + i * 16 + (lane & 15);
      int8v av = lds_op32(bA + ra * 128, ra, c2);
      #pragma unroll
      for (int j = 0; j < 4; ++j) {
        int rb = wn + j * 16 + (lane & 15);
        int8v bv = lds_op32(bB + rb * 128, rb, c2);
        acc[i][j] = __builtin_amdgcn_mfma_scale_f32_16x16x128_f8f6f4(
            av, bv, acc[i][j], 0, 0, 0, 0x7F7F7F7F, 0, 0x7F7F7F7F);
      }
    }
    __syncthreads();
  }
  const float RS = 0.0625f;            // undo weight x16

  if (EPI == 0 || EPI == 2) {
    #pragma unroll
    for (int i = 0; i < 4; ++i)
      #pragma unroll
      for (int j = 0; j < 4; ++j)
        #pragma unroll
        for (int r = 0; r < 4; ++r) {
          int m = m0 + wm + i * 16 + ((lane >> 4) << 2) + r;
          int n = n0 + wn + j * 16 + (lane & 15);
          float v = acc[i][j][r] * RS + bias[n];
          if (EPI == 0) {
            outb[(size_t)m * N + n] = __float2bfloat16(v);
          } else {
            float g = v / (1.0f + __expf(-1.702f * v));   // fast GELU (x1e-5 after ls2)
            out8[(size_t)m * N + n] = to_fp8(g);
          }
        }
  } else if (EPI == 1) {
    #pragma unroll
    for (int i = 0; i < 4; ++i)
      #pragma unroll
      for (int j = 0; j < 4; ++j)
        #pragma unroll
        for (int r = 0; r < 4; ++r) {
          int m = m0 + wm + i * 16 + ((lane >> 4) << 2) + r;
          int n = n0 + wn + j * 16 + (lane & 15);
          float v = acc[i][j][r] * RS + bias[n];
          v = __bfloat162float(resid[(size_t)m * CCH + n]) + ls[n] * v;
          outb[(size_t)m * CCH + n] = __float2bfloat16(v);
        }
  } else {   // EPI == 3 : epilogue + in-LDS transpose -> NCHW fp32, 4 passes of 32 n
    float* LT = (float*)lds;           // [32][132] fp32 = 16.9KB
    #pragma unroll 1
    for (int s = 0; s < 4; ++s) {
      __syncthreads();
      if (wn == (s >> 1) * 64) {
        const int j0 = (s & 1) * 2;
        #pragma unroll
        for (int i = 0; i < 4; ++i)
          #pragma unroll
          for (int jj = 0; jj < 2; ++jj)
            #pragma unroll
            for (int r = 0; r < 4; ++r) {
              int ml = wm + i * 16 + ((lane >> 4) << 2) + r;   // 0..127
              int nl = jj * 16 + (lane & 15);                   // 0..31
              int ng = n0 + s * 32 + nl;
              float v = acc[i][j0 + jj][r] * RS + bias[ng];
              v = __bfloat162float(resid[(size_t)(m0 + ml) * CCH + ng]) + ls[ng] * v;
              LT[nl * 132 + ml] = v;
            }
      }
      __syncthreads();
      #pragma unroll
      for (int u = 0; u < 4; ++u) {
        int q = tid + 256 * u;         // 0..1023 = 32 nl x 32 mq
        int nl = q >> 5;
        int mq = q & 31;
        int ng = n0 + s * 32 + nl;
        int ml = mq * 4;
        float4v v4 = *(const float4v*)(LT + nl * 132 + ml);
        int m = m0 + ml;
        int bb = m / NTOK, tt = m - bb * NTOK;   // tt multiple of 4; 196%4==0 -> no row cross
        *(float4v*)(outf + (size_t)bb * (CCH * NTOK) + (size_t)ng * NTOK + tt) = v4;
      }
    }
  }
}

// ---------------- attention: one block per (batch, head), bf16; fp8 out ----------------

__global__ __launch_bounds__(256, 2) void attn_kernel(
    const __hip_bfloat16* __restrict__ qkv, uint8_t* __restrict__ o_t8) {
  __shared__ char sQ[208 * 64];    // [208][32] bf16, chunk-swizzled rows
  __shared__ char sK[224 * 64];    // [224][32] bf16
  __shared__ char sV[32 * 448];    // V^T [32][224] bf16, chunk-swizzled
  __shared__ char sP[4][16 * 472]; // per-wave P [16][236] bf16
  const int tid  = threadIdx.x;
  const int lane = tid & 63;
  const int wave = tid >> 6;
  const int b = blockIdx.x >> 4;
  const int h = blockIdx.x & 15;
  const size_t qbase = (size_t)b * NTOK * 1536 + h * 32;

  {
    uint32_t* z = (uint32_t*)sQ;
    for (int i = tid; i < (208 * 64) / 4; i += 256) z[i] = 0u;
    z = (uint32_t*)sK;
    for (int i = tid; i < (224 * 64) / 4; i += 256) z[i] = 0u;
    z = (uint32_t*)sV;
    for (int i = tid; i < (32 * 448) / 4; i += 256) z[i] = 0u;
  }
  __syncthreads();

  for (int p = tid; p < NTOK * 4; p += 256) {
    int row = p >> 2, c = p & 3;
    const __hip_bfloat16* src = qkv + qbase + (size_t)row * 1536 + c * 8;
    short8v q = *(const short8v*)(src);
    short8v k = *(const short8v*)(src + 512);
    short8v v = *(const short8v*)(src + 1024);
    int pc = c ^ swz4(row);
    *(short8v*)(sQ + row * 64 + pc * 16) = q;
    *(short8v*)(sK + row * 64 + pc * 16) = k;
    #pragma unroll
    for (int j = 0; j < 8; ++j) {
      int d = c * 8 + j;
      int ch = (row >> 3) ^ swz4(d);
      *(uint16_t*)(sV + d * 448 + ch * 16 + (row & 7) * 2) = (uint16_t)v[j];
    }
  }
  __syncthreads();

  const float scale = 0.17677669529663687f;   // 1/sqrt(32)
  char* Pw = sP[wave];

  for (int mt = wave; mt < 13; mt += 4) {
    int qrow = mt * 16 + (lane & 15);
    int pcq = (lane >> 4) ^ swz4(qrow);
    short8v aq = *(const short8v*)(sQ + qrow * 64 + pcq * 16);

    float4v s[14];
    #pragma unroll
    for (int nt = 0; nt < 14; ++nt) {
      int krow = nt * 16 + (lane & 15);
      int pck = (lane >> 4) ^ swz4(krow);
      short8v bk = *(const short8v*)(sK + krow * 64 + pck * 16);
      s[nt] = float4v{0.f, 0.f, 0.f, 0.f};
      mfma16x16(s[nt], aq, bk);
    }
    asm volatile("s_nop 7\n\ts_nop 7");

    float mx[4] = {-INFINITY, -INFINITY, -INFINITY, -INFINITY};
    #pragma unroll
    for (int nt = 0; nt < 14; ++nt) {
      bool valid = (nt * 16 + (lane & 15)) < NTOK;
      #pragma unroll
      for (int r = 0; r < 4; ++r) {
        float v = valid ? s[nt][r] * scale : -INFINITY;
        s[nt][r] = v;
        mx[r] = fmaxf(mx[r], v);
      }
    }
    #pragma unroll
    for (int off = 1; off < 16; off <<= 1) {
      #pragma unroll
      for (int r = 0; r < 4; ++r) mx[r] = fmaxf(mx[r], __shfl_xor(mx[r], off));
    }
    float sum[4] = {0.f, 0.f, 0.f, 0.f};
    #pragma unroll
    for (int nt = 0; nt < 14; ++nt) {
      #pragma unroll
      for (int r = 0; r < 4; ++r) {
        float e = __expf(s[nt][r] - mx[r]);
        s[nt][r] = e;
        sum[r] += e;
      }
    }
    #pragma unroll
    for (int off = 1; off < 16; off <<= 1) {
      #pragma unroll
      for (int r = 0; r < 4; ++r) sum[r] += __shfl_xor(sum[r], off);
    }
    float rs[4];
    #pragma unroll
    for (int r = 0; r < 4; ++r) rs[r] = 1.0f / sum[r];

    #pragma unroll
    for (int nt = 0; nt < 14; ++nt) {
      int col = nt * 16 + (lane & 15);
      #pragma unroll
      for (int r = 0; r < 4; ++r) {
        int prow = ((lane >> 4) << 2) + r;
        *(__hip_bfloat16*)(Pw + prow * 472 + col * 2) = __float2bfloat16(s[nt][r] * rs[r]);
      }
    }

    float4v o0 = float4v{0.f, 0.f, 0.f, 0.f};
    float4v o1 = float4v{0.f, 0.f, 0.f, 0.f};
    #pragma unroll
    for (int ks = 0; ks < 7; ++ks) {
      short8v pa = *(const short8v*)(Pw + (lane & 15) * 472 + ks * 64 + ((lane >> 4) << 4));
      int kc = ks * 4 + (lane >> 4);
      int d0 = (lane & 15);
      int d1 = 16 + (lane & 15);
      short8v v0 = *(const short8v*)(sV + d0 * 448 + ((kc ^ swz4(d0)) << 4));
      short8v v1 = *(const short8v*)(sV + d1 * 448 + ((kc ^ swz4(d1)) << 4));
      mfma16x16(o0, pa, v0);
      mfma16x16(o1, pa, v1);
    }
    asm volatile("s_nop 7\n\ts_nop 7");

    #pragma unroll
    for (int r = 0; r < 4; ++r) {
      int trow = mt * 16 + ((lane >> 4) << 2) + r;
      if (trow < NTOK) {
        size_t ob = ((size_t)b * NTOK + trow) * CCH + h * 32 + (lane & 15);
        o_t8[ob] = to_fp8(o0[r]);
        o_t8[ob + 16] = to_fp8(o1[r]);
      }
    }
  }
}

// ---------------- depthwise 7x7 conv, token-major (+BN in, raw fp8 out) ----------------

__global__ __launch_bounds__(448) void dwconv_tm(
    const __hip_bfloat16* __restrict__ x1t, const float* __restrict__ dw_w,
    const float* __restrict__ cst, uint8_t* __restrict__ yt8) {
  __shared__ float img[196][32];
  __shared__ float wgt[49][32];
  const int tid = threadIdx.x;
  const int b  = blockIdx.x >> 4;
  const int cb = (blockIdx.x & 15) * 32;
  const int c  = tid & 31;
  const int gc = cb + c;
  const float s = cst[gc], t0 = cst[512 + gc];
  #pragma unroll
  for (int k = 0; k < 14; ++k) {
    int p = (tid >> 5) + k * 14;
    img[p][c] = __bfloat162float(x1t[((size_t)b * NTOK + p) * CCH + gc]) * s + t0;
  }
  for (int i = tid; i < 49 * 32; i += 448) {
    int tap = i >> 5, cc = i & 31;
    wgt[tap][cc] = dw_w[(cb + cc) * 49 + tap];
  }
  __syncthreads();

  const int px = tid >> 5;        // 0..13
  float out[14];
  #pragma unroll
  for (int i = 0; i < 14; ++i) out[i] = 0.f;
  #pragma unroll 1
  for (int row = 0; row < 14; ++row) {
    float v[7];
    #pragma unroll
    for (int dx = 0; dx < 7; ++dx) {
      int ix = px + dx - 3;
      v[dx] = ((unsigned)ix < 14u) ? img[row * 14 + ix][c] : 0.f;
    }
    #pragma unroll
    for (int kk = 0; kk < 7; ++kk) {
      int py = row + 3 - kk;
      if (py >= 0 && py < 14) {
        float hsum = 0.f;
        #pragma unroll
        for (int dx = 0; dx < 7; ++dx) hsum = fmaf(v[dx], wgt[kk * 7 + dx][c], hsum);
        out[py] += hsum;
      }
    }
  }
  #pragma unroll
  for (int py = 0; py < 14; ++py)
    yt8[((size_t)b * NTOK + py * 14 + px) * CCH + gc] = to_fp8(out[py]);
}

// ---------------- launch ----------------

extern "C" void kernel_launch(void* const* d_in, const int* in_sizes, int n_in,
                              void* d_out, int out_size, void* d_ws, size_t ws_size,
                              hipStream_t stream) {
  const float* x      = (const float*)d_in[0];
  const float* bn_g   = (const float*)d_in[1];
  const float* bn_b   = (const float*)d_in[2];
  const float* bn_m   = (const float*)d_in[3];
  const float* bn_v   = (const float*)d_in[4];
  const float* qkv_w  = (const float*)d_in[5];
  const float* proj_w = (const float*)d_in[6];
  const float* proj_b = (const float*)d_in[7];
  const float* dw_w   = (const float*)d_in[8];
  const float* fbn_g  = (const float*)d_in[9];
  const float* fbn_b  = (const float*)d_in[10];
  const float* fbn_m  = (const float*)d_in[11];
  const float* fbn_v  = (const float*)d_in[12];
  const float* fc1_w  = (const float*)d_in[13];
  const float* fc1_b  = (const float*)d_in[14];
  const float* fc2_w  = (const float*)d_in[15];
  const float* fc2_b  = (const float*)d_in[16];
  const float* ls1    = (const float*)d_in[17];
  const float* ls2    = (const float*)d_in[18];

  char* ws = (char*)d_ws;
  float* cst             = (float*)ws;                        // 8 KB
  float* qb              = (float*)(ws + 8192);               // 6 KB
  float* fb1             = (float*)(ws + 14336);              // 8 KB
  uint8_t* qkvb8         = (uint8_t*)(ws + 32768);            // 768 KB
  uint8_t* projb8        = (uint8_t*)(ws + 819200);           // 256 KB
  uint8_t* fc1b8         = (uint8_t*)(ws + 1081344);          // 1 MB
  uint8_t* fc2b8         = (uint8_t*)(ws + 2129920);          // 1 MB
  uint8_t* xt8           = (uint8_t*)(ws + 3178496);          // 6.4 MB
  __hip_bfloat16* xtb    = (__hip_bfloat16*)(ws + 9601024);   // 12.85 MB
  __hip_bfloat16* qkvt   = (__hip_bfloat16*)(ws + 22446080);  // 38.5 MB
  uint8_t* ot8           = (uint8_t*)(ws + 60981248);         // 6.4 MB
  __hip_bfloat16* x1t    = (__hip_bfloat16*)(ws + 67403776);  // 12.85 MB
  uint8_t* yt8           = (uint8_t*)(ws + 80248832);         // 6.4 MB (end 86.7 MB)
  uint8_t* h8            = (uint8_t*)(ws + 3178496);          // 25.7 MB overlay (xt8/xtb/qkvt dead)

  prep_consts<<<dim3(2), dim3(256), 0, stream>>>(bn_g, bn_b, bn_m, bn_v,
                                                 fbn_g, fbn_b, fbn_m, fbn_v, cst);
  cvt_weights<<<dim3(3072), dim3(256), 0, stream>>>(qkv_w, proj_w, fc1_w, fc2_w, cst,
                                                    qkvb8, projb8, fc1b8, fc2b8);
  prep_bias<<<dim3(3584), dim3(128), 0, stream>>>(qkv_w, fc1_w, fc1_b, cst, qb, fb1);
  transpose_x<<<dim3(7, 16, 64), dim3(256), 0, stream>>>(x, xtb, xt8);
  // QKV: M=12544, N=1536, K=512 ; 128x128 -> 98*12 = 1176 blocks
  gemm8<0><<<dim3(1176), dim3(256), 0, stream>>>(xt8, qkvb8, 1536, 512, 12,
                                                 qkvt, nullptr, nullptr, qb, nullptr, nullptr);
  attn_kernel<<<dim3(1024), dim3(256), 0, stream>>>(qkvt, ot8);
  // proj: N=512, K=512 ; 98*4 = 392 blocks
  gemm8<1><<<dim3(392), dim3(256), 0, stream>>>(ot8, projb8, 512, 512, 4,
                                                x1t, nullptr, nullptr, proj_b, ls1, xtb);
  dwconv_tm<<<dim3(1024), dim3(448), 0, stream>>>(x1t, dw_w, cst, yt8);
  // fc1: N=2048, K=512 ; 98*16 = 1568 blocks
  gemm8<2><<<dim3(1568), dim3(256), 0, stream>>>(yt8, fc1b8, 2048, 512, 16,
                                                 nullptr, h8, nullptr, fb1, nullptr, nullptr);
  // fc2: N=512, K=2048 ; 392 blocks ; NCHW fp32 out
  gemm8<3><<<dim3(392), dim3(256), 0, stream>>>(h8, fc2b8, 512, 2048, 4,
                                                nullptr, nullptr, (float*)d_out, fc2_b, ls2, x1t);
}